// Round 6
// baseline (194.794 us; speedup 1.0000x reference)
//
#include <hip/hip_runtime.h>
#include <math.h>

// Problem constants (fixed by setup_inputs)
#define BATCH 4
#define CCH   256   // channels
#define DQK   32    // q/k channels
#define NPIX  4096  // H*W
#define LOG2E 1.44269504088896340736f

typedef __attribute__((ext_vector_type(8)))  short          short8_t;
typedef __attribute__((ext_vector_type(4)))  unsigned short ushort4_t;
typedef __attribute__((ext_vector_type(8)))  unsigned short ushort8_t;
typedef __attribute__((ext_vector_type(16))) float          f32x16;
typedef __attribute__((ext_vector_type(2)))  unsigned int   uint2_t;

#if __has_builtin(__builtin_amdgcn_exp2f)
#define EXP2F(x) __builtin_amdgcn_exp2f(x)
#else
#define EXP2F(x) exp2f(x)
#endif

#define MFMA32(a, b, c) __builtin_amdgcn_mfma_f32_32x32x16_bf16(a, b, c, 0, 0, 0)

static __device__ __forceinline__ unsigned short f2bf(float f) {
    union { float f; unsigned int u; } v; v.f = f;
    unsigned int r = v.u + 0x7FFFu + ((v.u >> 16) & 1u);   // RNE
    return (unsigned short)(r >> 16);
}

static __device__ __forceinline__ short8_t cat8(ushort4_t a, ushort4_t b) {
    ushort8_t c = __builtin_shufflevector(a, b, 0, 1, 2, 3, 4, 5, 6, 7);
    short8_t r; __builtin_memcpy(&r, &c, 16); return r;
}

static __device__ __forceinline__ short8_t u4_to_s8(const unsigned int* u) {
    short8_t r; __builtin_memcpy(&r, u, 16); return r;
}

// permlane32_swap(a,b) -> {x = {a_lo32lanes, b_lo32lanes}, y = {a_hi, b_hi}}
static __device__ __forceinline__ uint2_t plswap(unsigned int a, unsigned int b) {
#if __has_builtin(__builtin_amdgcn_permlane32_swap)
    return __builtin_amdgcn_permlane32_swap(a, b, false, false);
#else
    const unsigned int sa = (unsigned int)__shfl_xor((int)a, 32);
    const unsigned int sb = (unsigned int)__shfl_xor((int)b, 32);
    const int h = (threadIdx.x >> 5) & 1;
    uint2_t r;
    r.x = h ? sb : a;
    r.y = h ? b : sa;
    return r;
#endif
}

// S (C-layout, packed bf16 pairs P[0..7]) -> PV B-operand fragments
static __device__ __forceinline__ void make_bfrag(
    const f32x16& s, float& l0, float& l1, unsigned int bfr[2][4])
{
    float pv[16];
    #pragma unroll
    for (int r = 0; r < 16; ++r) pv[r] = EXP2F(s[r]);
    #pragma unroll
    for (int r = 0; r < 16; r += 2) { l0 += pv[r]; l1 += pv[r + 1]; }
    unsigned int P[8];
    #pragma unroll
    for (int v = 0; v < 8; ++v)
        P[v] = __builtin_amdgcn_perm(__float_as_uint(pv[2 * v + 1]),
                                     __float_as_uint(pv[2 * v]), 0x07060302u);
    #pragma unroll
    for (int kp = 0; kp < 2; ++kp) {
        const uint2_t r02 = plswap(P[4 * kp + 0], P[4 * kp + 2]);
        const uint2_t r13 = plswap(P[4 * kp + 1], P[4 * kp + 3]);
        bfr[kp][0] = r02.x; bfr[kp][1] = r13.x;
        bfr[kp][2] = r02.y; bfr[kp][3] = r13.y;
    }
}

// ---------------------------------------------------------------------------
// Stage 0: weights -> bf16 in A-fragment-coalesced layout:
//   wT[((k>>3)*320 + o)*8 + (k&7)]; o: 0-31 Wq (x log2e), 32-63 Wk, 64-319 Wv.
// ---------------------------------------------------------------------------
__global__ __launch_bounds__(256) void wconv_kernel(
    const float* __restrict__ Wq, const float* __restrict__ Wk,
    const float* __restrict__ Wv, unsigned short* __restrict__ wbf)
{
    const int idx = blockIdx.x * 256 + threadIdx.x;   // grid 320 -> 81920
    const int o = idx >> 8, c = idx & 255;
    float v;
    if (o < 32)      v = Wq[o * 256 + c] * LOG2E;
    else if (o < 64) v = Wk[(o - 32) * 256 + c];
    else             v = Wv[(o - 64) * 256 + c];
    wbf[((c >> 3) * 320 + o) * 8 + (c & 7)] = f2bf(v);
}

// ---------------------------------------------------------------------------
// Stage 1: MFMA projections. D[o=320][px] = W[o][c] * x[c][px] per batch.
// Block = (b, 32-px tile) -> grid 512, 320 threads = 5 waves (wave w: o 64w..).
// x tile staged in LDS bf16 [px][c] XOR-swizzled; W streamed coalesced.
// q/k outputs transposed through LDS (same-wave) for coalesced b128 stores.
// ---------------------------------------------------------------------------
__global__ __launch_bounds__(320) void proj_kernel(
    const float* __restrict__ x, const unsigned short* __restrict__ wbf,
    const float* __restrict__ bq, const float* __restrict__ bk,
    const float* __restrict__ bv,
    unsigned short* __restrict__ q_bf, unsigned short* __restrict__ k_bf,
    unsigned short* __restrict__ v_bf)
{
    __shared__ unsigned short xs[32 * 256];    // 16 KB
    __shared__ unsigned short qk[2 * 32 * 36]; // 4.5 KB transpose buffer
    const int b  = blockIdx.x >> 7;
    const int n0 = (blockIdx.x & 127) << 5;
    const int t  = threadIdx.x;

    if (t < 256) {   // waves 0-3 stage; wave 4 waits at barrier
        const int px = t & 31, cg = t >> 5;   // cg in [0,8)
        const float* xp = x + ((size_t)b * CCH + cg * 32) * NPIX + n0 + px;
        unsigned short* row = xs + px * 256;
        const int sw = px & 15;
        #pragma unroll
        for (int cc = 0; cc < 32; cc += 2) {
            const float a0 = xp[(size_t)cc * NPIX];
            const float a1 = xp[(size_t)(cc + 1) * NPIX];
            const unsigned int pk = __builtin_amdgcn_perm(
                __float_as_uint(a1), __float_as_uint(a0), 0x07060302u);
            const int c = cg * 32 + cc;
            *(unsigned int*)&row[(((c >> 2) ^ sw) << 2) + (c & 3)] = pk;
        }
    }
    __syncthreads();

    const int w = t >> 6, lane = t & 63, il = lane & 31, h = lane >> 5;

    // bias prefetch: lane needs bias[base + 8g + 4h + (0..3)] for g = r>>2
    float4 bA[4], bB[4];
    #pragma unroll
    for (int g = 0; g < 4; ++g) {
        if (w == 0) {
            bA[g] = *(const float4*)&bq[8 * g + 4 * h];
            bB[g] = *(const float4*)&bk[8 * g + 4 * h];
        } else {
            bA[g] = *(const float4*)&bv[(w - 1) * 64 + 8 * g + 4 * h];
            bB[g] = *(const float4*)&bv[(w - 1) * 64 + 32 + 8 * g + 4 * h];
        }
    }

    f32x16 acc0, acc1;
    #pragma unroll
    for (int r = 0; r < 16; ++r) { acc0[r] = 0.f; acc1[r] = 0.f; }

    const unsigned short* wp = wbf + ((size_t)(h * 320 + w * 64 + il)) * 8;
    const unsigned short* xrow = xs + il * 256;
    const int sw = il & 15;

    #pragma unroll 4
    for (int ks = 0; ks < 16; ++ks) {
        short8_t af0 = *(const short8_t*)(wp + ks * 5120);        // o-rows w*64..+31
        short8_t af1 = *(const short8_t*)(wp + ks * 5120 + 256);  // o-rows w*64+32..+63
        const int k0c = ks * 4 + h * 2;
        ushort4_t lo = *(const ushort4_t*)&xrow[((k0c    ) ^ sw) << 2];
        ushort4_t hi = *(const ushort4_t*)&xrow[((k0c + 1) ^ sw) << 2];
        short8_t bfr = cat8(lo, hi);
        acc0 = MFMA32(af0, bfr, acc0);
        acc1 = MFMA32(af1, bfr, acc1);
    }

    // epilogue. D: col=il=px, row o = (r&3)+8*(r>>2)+4h
    if (w == 0) {
        // q/k: transpose via LDS (same-wave only -> no barrier), coalesced stores
        #pragma unroll
        for (int r = 0; r < 16; ++r) {
            const int orow = (r & 3) + 8 * (r >> 2) + 4 * h;
            qk[il * 36 + orow]        = f2bf(acc0[r] + bA[r >> 2][r & 3] * LOG2E);
            qk[1152 + il * 36 + orow] = f2bf(acc1[r] + bB[r >> 2][r & 3]);
        }
        #pragma unroll
        for (int rep = 0; rep < 2; ++rep) {
            const int chunk = rep * 64 + lane;
            const int px = chunk >> 2, oq = chunk & 3;
            ushort4_t qlo = *(const ushort4_t*)&qk[px * 36 + oq * 8];
            ushort4_t qhi = *(const ushort4_t*)&qk[px * 36 + oq * 8 + 4];
            ushort4_t klo = *(const ushort4_t*)&qk[1152 + px * 36 + oq * 8];
            ushort4_t khi = *(const ushort4_t*)&qk[1152 + px * 36 + oq * 8 + 4];
            *(short8_t*)&q_bf[((size_t)(b * NPIX + n0 + px)) * 32 + oq * 8] = cat8(qlo, qhi);
            *(short8_t*)&k_bf[((size_t)(b * NPIX + n0 + px)) * 32 + oq * 8] = cat8(klo, khi);
        }
    } else {
        const int px = n0 + il;
        #pragma unroll
        for (int r = 0; r < 16; ++r) {
            const int orow = (r & 3) + 8 * (r >> 2) + 4 * h;
            const int c0 = (w - 1) * 64 + orow;
            v_bf[((size_t)(b * CCH + c0))      * NPIX + px] = f2bf(acc0[r] + bA[r >> 2][r & 3]);
            v_bf[((size_t)(b * CCH + c0 + 32)) * NPIX + px] = f2bf(acc1[r] + bB[r >> 2][r & 3]);
        }
    }
}

// ---------------------------------------------------------------------------
// Stage 2: MFMA flash attention, double-buffered LDS, 1 barrier/tile.
// Block = (b, 32-query tile), 256 thr = 4 waves; wave w = channels w*64..+63.
// All waves walk the full j range (no split -> no combine). Grid 512
// (2 blocks/CU); XCD-aware mapping: blk%8 encodes batch so each XCD's L2
// caches one batch's V (2 MB < 4 MB).
// LDS rows: 32 elems padded to 40 (80 B), 16B slots XOR-swizzled with
// swz=(row>>3)&3 -> fragment reads hit all 32 banks (conflict-free),
// staged writes <=2-way (free).
// ---------------------------------------------------------------------------
#define RST   40
#define VOFF  (32 * RST)           // K region: 32 rows
#define BSTR  (VOFF + 256 * RST)   // + V region: 256 rows = 11520 elems/buffer

__global__ __launch_bounds__(256) void attn_kernel(
    const unsigned short* __restrict__ qb,   // [B][N][32] bf16 (x log2e)
    const unsigned short* __restrict__ kb,   // [B][N][32] bf16
    const unsigned short* __restrict__ vb,   // [B][C][N] bf16
    const float* __restrict__ x,             // [B][C][N] fp32
    const float* __restrict__ gamma,
    float* __restrict__ out)
{
    __shared__ unsigned short lds[2 * BSTR]; // 45 KB

    // XCD-aware decode: blk = (idx>>1)*8 + 2b + (idx&1)
    const int m8 = blockIdx.x & 7;
    const int b  = m8 >> 1;
    const int i0 = ((((blockIdx.x >> 3) << 1) | (m8 & 1))) << 5;
    const int t  = threadIdx.x;
    const int w = t >> 6, lane = t & 63, il = lane & 31, h = lane >> 5;
    const int cbase = w * 64;
    const int swz = (il >> 3) & 3;

    // ---- staging maps (coalesced global, swizzled LDS) ----
    const unsigned short* vgp[4];
    int vlo[4];
    #pragma unroll
    for (int r = 0; r < 4; ++r) {
        const int u = r * 256 + t;           // 1024 V chunks of 8 elems
        const int c = u >> 2, q = u & 3;
        vgp[r] = vb + ((size_t)(b * CCH + c)) * NPIX + q * 8;
        vlo[r] = VOFF + c * RST + ((q ^ ((c >> 3) & 3)) << 3);
    }
    const int kr = t >> 2, kq = t & 3;       // 128 K chunks (t < 128)
    const unsigned short* kgp = kb + ((size_t)(b * NPIX + kr)) * 32 + kq * 8;
    const int klo = kr * RST + ((kq ^ ((kr >> 3) & 3)) << 3);

    // ---- fragment read offsets ----
    const int kfo0 = il * RST + (((h    ) ^ swz) << 3);
    const int kfo1 = il * RST + (((2 + h) ^ swz) << 3);
    int vfo[2][2];
    #pragma unroll
    for (int ct = 0; ct < 2; ++ct)
        #pragma unroll
        for (int kp = 0; kp < 2; ++kp)
            vfo[ct][kp] = VOFF + (cbase + ct * 32 + il) * RST +
                          (((kp * 2 + h) ^ swz) << 3);

    // ---- Q fragments (B-operand): lane n=il, k = ks*16 + h*8 ----
    const unsigned short* qp = qb + ((size_t)(b * NPIX + i0 + il)) * 32 + h * 8;
    const short8_t qf0 = *(const short8_t*)qp;
    const short8_t qf1 = *(const short8_t*)(qp + 16);

    f32x16 zf;
    #pragma unroll
    for (int r = 0; r < 16; ++r) zf[r] = 0.f;
    f32x16 acc0 = zf, acc1 = zf;
    float ls0 = 0.f, ls1 = 0.f;

    short8_t sV0[4], sV1[4], sK0, sK1;

    auto load_stage = [&](short8_t* sv, short8_t& sk, int jt) {
        const int j0 = jt * 32;
        #pragma unroll
        for (int r = 0; r < 4; ++r) sv[r] = *(const short8_t*)(vgp[r] + j0);
        if (t < 128) sk = *(const short8_t*)(kgp + (size_t)j0 * 32);
    };
    auto store_stage = [&](short8_t* sv, short8_t& sk, int base) {
        #pragma unroll
        for (int r = 0; r < 4; ++r) *(short8_t*)(lds + base + vlo[r]) = sv[r];
        if (t < 128) *(short8_t*)(lds + base + klo) = sk;
    };
    auto compute = [&](int base) {
        const short8_t kf0 = *(const short8_t*)(lds + base + kfo0);
        const short8_t kf1 = *(const short8_t*)(lds + base + kfo1);
        f32x16 s = MFMA32(kf0, qf0, zf);
        s = MFMA32(kf1, qf1, s);
        unsigned int bfr[2][4];
        make_bfrag(s, ls0, ls1, bfr);
        const short8_t vf00 = *(const short8_t*)(lds + base + vfo[0][0]);
        const short8_t vf01 = *(const short8_t*)(lds + base + vfo[0][1]);
        const short8_t vf10 = *(const short8_t*)(lds + base + vfo[1][0]);
        const short8_t vf11 = *(const short8_t*)(lds + base + vfo[1][1]);
        acc0 = MFMA32(vf00, u4_to_s8(bfr[0]), acc0);
        acc0 = MFMA32(vf01, u4_to_s8(bfr[1]), acc0);
        acc1 = MFMA32(vf10, u4_to_s8(bfr[0]), acc1);
        acc1 = MFMA32(vf11, u4_to_s8(bfr[1]), acc1);
    };

    // ---- software pipeline: 2 tiles in regs, 2 in LDS ----
    load_stage(sV0, sK0, 0);
    load_stage(sV1, sK1, 1);
    store_stage(sV0, sK0, 0);
    __syncthreads();
    for (int jt = 0; jt < 126; jt += 2) {
        store_stage(sV1, sK1, BSTR);       // tile jt+1 -> buf1
        load_stage(sV0, sK0, jt + 2);      // prefetch jt+2
        compute(0);                        // tile jt
        __syncthreads();
        store_stage(sV0, sK0, 0);          // tile jt+2 -> buf0
        load_stage(sV1, sK1, jt + 3);      // prefetch jt+3
        compute(BSTR);                     // tile jt+1
        __syncthreads();
    }
    store_stage(sV1, sK1, BSTR);           // tile 127 -> buf1
    compute(0);                            // tile 126
    __syncthreads();
    compute(BSTR);                         // tile 127

    // ---- epilogue: out = x + (gamma/l) * O^T  (no LDS exchange needed) ----
    float lsum = ls0 + ls1;
    lsum += __shfl_xor(lsum, 32);          // combine h halves of j rows
    const float sc = gamma[0] / lsum;

    #pragma unroll
    for (int ct = 0; ct < 2; ++ct) {
        const f32x16& a = ct ? acc1 : acc0;
        #pragma unroll
        for (int r = 0; r < 16; ++r) {
            const int c = cbase + ct * 32 + (r & 3) + 8 * (r >> 2) + 4 * h;
            const size_t idx = ((size_t)(b * CCH + c)) * NPIX + i0 + il;
            out[idx] = x[idx] + a[r] * sc;
        }
    }
}

// ---------------------------------------------------------------------------
// Workspace (bf16 elems): wbf[81920] | q_bf[524288] | k_bf[524288] | v_bf[4194304]
// = 10.2 MB total.
// ---------------------------------------------------------------------------
extern "C" void kernel_launch(void* const* d_in, const int* in_sizes, int n_in,
                              void* d_out, int out_size, void* d_ws, size_t ws_size,
                              hipStream_t stream) {
    const float* x     = (const float*)d_in[0];
    const float* Wq    = (const float*)d_in[1];
    const float* bq    = (const float*)d_in[2];
    const float* Wk    = (const float*)d_in[3];
    const float* bk    = (const float*)d_in[4];
    const float* Wv    = (const float*)d_in[5];
    const float* bv    = (const float*)d_in[6];
    const float* gamma = (const float*)d_in[7];
    float* out = (float*)d_out;

    unsigned short* ws  = (unsigned short*)d_ws;
    unsigned short* wbf = ws;
    unsigned short* qbf = ws + 81920;
    unsigned short* kbf = qbf + (size_t)BATCH * NPIX * DQK;
    unsigned short* vbf = kbf + (size_t)BATCH * NPIX * DQK;

    wconv_kernel<<<dim3(320), dim3(256), 0, stream>>>(Wq, Wk, Wv, wbf);
    proj_kernel<<<dim3(BATCH * (NPIX / 32)), dim3(320), 0, stream>>>(
        x, wbf, bq, bk, bv, qbf, kbf, vbf);
    attn_kernel<<<dim3(BATCH * (NPIX / 32)), dim3(256), 0, stream>>>(
        qbf, kbf, vbf, x, gamma, out);
}

// Round 7
// 154.195 us; speedup vs baseline: 1.2633x; 1.2633x over previous
//
#include <hip/hip_runtime.h>
#include <math.h>

// Problem constants (fixed by setup_inputs)
#define BATCH 4
#define CCH   256   // channels
#define DQK   32    // q/k channels
#define NPIX  4096  // H*W
#define LOG2E 1.44269504088896340736f

typedef __attribute__((ext_vector_type(8)))  short          short8_t;
typedef __attribute__((ext_vector_type(4)))  unsigned short ushort4_t;
typedef __attribute__((ext_vector_type(8)))  unsigned short ushort8_t;
typedef __attribute__((ext_vector_type(16))) float          f32x16;
typedef __attribute__((ext_vector_type(2)))  unsigned int   uint2_t;

#if __has_builtin(__builtin_amdgcn_exp2f)
#define EXP2F(x) __builtin_amdgcn_exp2f(x)
#else
#define EXP2F(x) exp2f(x)
#endif

#define MFMA32(a, b, c) __builtin_amdgcn_mfma_f32_32x32x16_bf16(a, b, c, 0, 0, 0)

static __device__ __forceinline__ unsigned short f2bf(float f) {
    union { float f; unsigned int u; } v; v.f = f;
    unsigned int r = v.u + 0x7FFFu + ((v.u >> 16) & 1u);   // RNE
    return (unsigned short)(r >> 16);
}

static __device__ __forceinline__ short8_t cat8(ushort4_t a, ushort4_t b) {
    ushort8_t c = __builtin_shufflevector(a, b, 0, 1, 2, 3, 4, 5, 6, 7);
    short8_t r; __builtin_memcpy(&r, &c, 16); return r;
}

static __device__ __forceinline__ short8_t u4_to_s8(const unsigned int* u) {
    short8_t r; __builtin_memcpy(&r, u, 16); return r;
}

// permlane32_swap(a,b) -> {x = {a_lo32lanes, b_lo32lanes}, y = {a_hi, b_hi}}
static __device__ __forceinline__ uint2_t plswap(unsigned int a, unsigned int b) {
#if __has_builtin(__builtin_amdgcn_permlane32_swap)
    return __builtin_amdgcn_permlane32_swap(a, b, false, false);
#else
    const unsigned int sa = (unsigned int)__shfl_xor((int)a, 32);
    const unsigned int sb = (unsigned int)__shfl_xor((int)b, 32);
    const int h = (threadIdx.x >> 5) & 1;
    uint2_t r;
    r.x = h ? sb : a;
    r.y = h ? b : sa;
    return r;
#endif
}

// S (C-layout) -> exp2 -> packed bf16 PV B-operand fragments; accumulates l
static __device__ __forceinline__ void make_bfrag(
    const f32x16& s, float& l0, float& l1, unsigned int bfr[2][4])
{
    float pv[16];
    #pragma unroll
    for (int r = 0; r < 16; ++r) pv[r] = EXP2F(s[r]);
    #pragma unroll
    for (int r = 0; r < 16; r += 2) { l0 += pv[r]; l1 += pv[r + 1]; }
    unsigned int P[8];
    #pragma unroll
    for (int v = 0; v < 8; ++v)
        P[v] = __builtin_amdgcn_perm(__float_as_uint(pv[2 * v + 1]),
                                     __float_as_uint(pv[2 * v]), 0x07060302u);
    #pragma unroll
    for (int kp = 0; kp < 2; ++kp) {
        const uint2_t r02 = plswap(P[4 * kp + 0], P[4 * kp + 2]);
        const uint2_t r13 = plswap(P[4 * kp + 1], P[4 * kp + 3]);
        bfr[kp][0] = r02.x; bfr[kp][1] = r13.x;
        bfr[kp][2] = r02.y; bfr[kp][3] = r13.y;
    }
}

// ---------------------------------------------------------------------------
// Stage 0a: weights -> bf16 A-fragment layout wbf[((c>>3)*320 + o)*8 + (c&7)]
// (o: 0-31 Wq x log2e, 32-63 Wk, 64-319 Wv).
// ---------------------------------------------------------------------------
__global__ __launch_bounds__(256) void wconv_kernel(
    const float* __restrict__ Wq, const float* __restrict__ Wk,
    const float* __restrict__ Wv, unsigned short* __restrict__ wbf)
{
    const int idx = blockIdx.x * 256 + threadIdx.x;   // grid 320 -> 81920
    const int o = idx >> 8, c = idx & 255;
    float v;
    if (o < 32)      v = Wq[o * 256 + c] * LOG2E;
    else if (o < 64) v = Wk[(o - 32) * 256 + c];
    else             v = Wv[(o - 64) * 256 + c];
    wbf[((c >> 3) * 320 + o) * 8 + (c & 7)] = f2bf(v);
}

// ---------------------------------------------------------------------------
// Stage 0b: x (fp32 [b][c][n]) -> bf16 B-fragment layout
//   xfrag[(((b*128 + nt)*32 + slot)*32 + il)*8 + e],  c = slot*8+e, n = nt*32+il
// Register-only transpose: block = (b, cg in 4, ng in 16) covers 64c x 256n.
// Reads: 256B bursts; writes: dense coalesced 16B/lane runs.
// ---------------------------------------------------------------------------
__global__ __launch_bounds__(256) void xt_kernel(
    const float* __restrict__ x, unsigned short* __restrict__ xfrag)
{
    const int b  = blockIdx.x >> 6;
    const int cg = (blockIdx.x >> 4) & 3;
    const int ng = blockIdx.x & 15;
    const int t  = threadIdx.x;
    const int w = t >> 6, l = t & 63;

    #pragma unroll
    for (int sgl = 0; sgl < 2; ++sgl) {
        const int sg = w * 2 + sgl;          // block-local c-octet, 0..7
        float f[4][8];
        #pragma unroll
        for (int p = 0; p < 8; ++p) {
            const float* row = x + ((size_t)(b * CCH + cg * 64 + sg * 8 + p)) * NPIX
                                 + ng * 256;
            #pragma unroll
            for (int j = 0; j < 4; ++j)
                f[j][p] = row[j * 64 + l];
        }
        #pragma unroll
        for (int j = 0; j < 4; ++j) {
            unsigned int d[4];
            #pragma unroll
            for (int k = 0; k < 4; ++k)
                d[k] = __builtin_amdgcn_perm(__float_as_uint(f[j][2 * k + 1]),
                                             __float_as_uint(f[j][2 * k]), 0x07060302u);
            const int nt = ng * 8 + j * 2 + (l >> 5);
            unsigned short* dst = xfrag +
                ((((size_t)(b * 128 + nt) * 32) + cg * 8 + sg) * 32 + (l & 31)) * 8;
            *(short8_t*)dst = u4_to_s8(d);
        }
    }
}

// ---------------------------------------------------------------------------
// Stage 1: LDS-free MFMA projections. D[o=320][n] = W[o][c] * x[c][n].
// Block = (b, 64-n tile), grid 256, 320 thr = 5 waves (wave w: o = 64w..).
// K-loop: W A-frags + xfrag B-frags, all coalesced global loads, no barriers.
// Epilogue: per-wave LDS transpose (no barriers) into fragment layouts:
//   qfrag/kfrag[(((b*128+jt)*4 + dslot)*32 + n&31)*8]   (8 d-elems per chunk)
//   vfrag[(((b*128+jt)*4 + jslot)*256 + c)*8]           (8 j-elems per chunk)
// ---------------------------------------------------------------------------
__global__ __launch_bounds__(320) void proj_kernel(
    const unsigned short* __restrict__ xfrag, const unsigned short* __restrict__ wbf,
    const float* __restrict__ bq, const float* __restrict__ bk,
    const float* __restrict__ bv,
    unsigned short* __restrict__ qfrag, unsigned short* __restrict__ kfrag,
    unsigned short* __restrict__ vfrag)
{
    __shared__ unsigned short qkb[2 * 2 * 32 * 40];  // [it][q/k][n 32][d 32+pad]
    __shared__ unsigned short vbuf[4 * 64 * 72];     // per v-wave [c 64][n 64+pad]

    const int b   = blockIdx.x >> 6;
    const int nt0 = (blockIdx.x & 63) << 1;          // first 32-n tile of this block
    const int t   = threadIdx.x;
    const int w = t >> 6, lane = t & 63, il = lane & 31, h = lane >> 5;

    // bias prefetch (lane needs base + 8g + 4h + 0..3 for g = r>>2)
    float4 bA[4], bB[4];
    #pragma unroll
    for (int g = 0; g < 4; ++g) {
        if (w == 0) {
            bA[g] = *(const float4*)&bq[8 * g + 4 * h];
            bB[g] = *(const float4*)&bk[8 * g + 4 * h];
        } else {
            bA[g] = *(const float4*)&bv[(w - 1) * 64 + 8 * g + 4 * h];
            bB[g] = *(const float4*)&bv[(w - 1) * 64 + 32 + 8 * g + 4 * h];
        }
    }

    f32x16 acc[2][2];   // [o-half][it]
    #pragma unroll
    for (int a = 0; a < 2; ++a)
        #pragma unroll
        for (int i = 0; i < 2; ++i)
            #pragma unroll
            for (int r = 0; r < 16; ++r) acc[a][i][r] = 0.f;

    const unsigned short* wp = wbf + ((size_t)(h * 320 + w * 64 + il)) * 8;
    const unsigned short* xp0 = xfrag + (((size_t)(b * 128 + nt0) * 32 + h) * 32 + il) * 8;
    const unsigned short* xp1 = xp0 + (size_t)32 * 32 * 8;   // nt0+1

    #pragma unroll 4
    for (int ks = 0; ks < 16; ++ks) {
        const short8_t af0 = *(const short8_t*)(wp + ks * 5120);
        const short8_t af1 = *(const short8_t*)(wp + ks * 5120 + 256);
        const short8_t bf0 = *(const short8_t*)(xp0 + (size_t)ks * 2 * 256);
        const short8_t bf1 = *(const short8_t*)(xp1 + (size_t)ks * 2 * 256);
        acc[0][0] = MFMA32(af0, bf0, acc[0][0]);
        acc[0][1] = MFMA32(af0, bf1, acc[0][1]);
        acc[1][0] = MFMA32(af1, bf0, acc[1][0]);
        acc[1][1] = MFMA32(af1, bf1, acc[1][1]);
    }

    // ---- epilogue (same-wave LDS transposes only; zero barriers) ----
    if (w == 0) {
        // q = acc[0][it], k = acc[1][it].  C: col=il=n, row d = (r&3)+8*(r>>2)+4h
        #pragma unroll
        for (int it = 0; it < 2; ++it)
            #pragma unroll
            for (int r = 0; r < 16; ++r) {
                const int d = (r & 3) + 8 * (r >> 2) + 4 * h;
                qkb[(it * 2 + 0) * 1280 + il * 40 + d] =
                    f2bf(acc[0][it][r] + bA[r >> 2][r & 3] * LOG2E);
                qkb[(it * 2 + 1) * 1280 + il * 40 + d] =
                    f2bf(acc[1][it][r] + bB[r >> 2][r & 3]);
            }
        #pragma unroll
        for (int it = 0; it < 2; ++it)
            #pragma unroll
            for (int rep = 0; rep < 2; ++rep) {
                const int u = rep * 64 + lane;       // 128 chunks: slot(4) x n(32)
                const int slot = u >> 5, n = u & 31;
                ushort4_t qlo = *(const ushort4_t*)&qkb[(it * 2) * 1280 + n * 40 + slot * 8];
                ushort4_t qhi = *(const ushort4_t*)&qkb[(it * 2) * 1280 + n * 40 + slot * 8 + 4];
                ushort4_t klo = *(const ushort4_t*)&qkb[(it * 2 + 1) * 1280 + n * 40 + slot * 8];
                ushort4_t khi = *(const ushort4_t*)&qkb[(it * 2 + 1) * 1280 + n * 40 + slot * 8 + 4];
                const size_t o8 = (((size_t)(b * 128 + nt0 + it) * 4 + slot) * 32 + n) * 8;
                *(short8_t*)(qfrag + o8) = cat8(qlo, qhi);
                *(short8_t*)(kfrag + o8) = cat8(klo, khi);
            }
    } else {
        unsigned short* vb = vbuf + (w - 1) * 64 * 72;   // [c 64][n 64 pad 72]
        #pragma unroll
        for (int it = 0; it < 2; ++it)
            #pragma unroll
            for (int r = 0; r < 16; ++r) {
                const int orow = (r & 3) + 8 * (r >> 2) + 4 * h;
                vb[(orow)      * 72 + it * 32 + il] = f2bf(acc[0][it][r] + bA[r >> 2][r & 3]);
                vb[(orow + 32) * 72 + it * 32 + il] = f2bf(acc[1][it][r] + bB[r >> 2][r & 3]);
            }
        #pragma unroll
        for (int rep = 0; rep < 8; ++rep) {
            const int u = rep * 64 + lane;   // 512 chunks: (it,slot)(8) x c(64)
            const int c = u & 63, m = u >> 6;
            const int it = m >> 2, slot = m & 3;
            ushort4_t lo = *(const ushort4_t*)&vb[c * 72 + it * 32 + slot * 8];
            ushort4_t hi = *(const ushort4_t*)&vb[c * 72 + it * 32 + slot * 8 + 4];
            const size_t o8 = (((size_t)(b * 128 + nt0 + it) * 4 + slot) * 256 +
                               (w - 1) * 64 + c) * 8;
            *(short8_t*)(vfrag + o8) = cat8(lo, hi);
        }
    }
}

// ---------------------------------------------------------------------------
// Stage 2: MFMA flash attention — ZERO LDS / barriers in the main loop.
// Block = (b, 64-query tile), 512 thr = 8 waves (ci = w&3 channels, jj = w>>2
// j-half). All loads coalesced from fragment layouts; register double-buffer.
// p = exp2(s) un-normalized => disjoint-j partials add linearly; one small
// LDS combine at the end. Grid 256, XCD-batch affinity via blk%8.
// ---------------------------------------------------------------------------
struct Stage { short8_t k0, k1, v00, v01, v10, v11; };

__global__ __launch_bounds__(512) void attn_kernel(
    const unsigned short* __restrict__ qfrag,
    const unsigned short* __restrict__ kfrag,
    const unsigned short* __restrict__ vfrag,
    const float* __restrict__ x,             // [B][C][N] fp32
    const float* __restrict__ gamma,
    float* __restrict__ out)
{
    __shared__ float comb[8][64][17];        // 34.8 KB, end-combine only

    const int m8 = blockIdx.x & 7;
    const int b  = m8 >> 1;
    const int itile = ((blockIdx.x >> 3) << 1) | (m8 & 1);   // 0..63
    const int i0 = itile << 6;
    const int t  = threadIdx.x;
    const int w = t >> 6, lane = t & 63, il = lane & 31, h = lane >> 5;
    const int ci = w & 3, jj = w >> 2;
    const int cbase = ci * 64;

    // Q fragments: chunk (nt = itile*2+it, slot = ks*2+h, il)
    short8_t qf[2][2];
    #pragma unroll
    for (int it = 0; it < 2; ++it)
        #pragma unroll
        for (int ks = 0; ks < 2; ++ks)
            qf[it][ks] = *(const short8_t*)(qfrag +
                (((size_t)(b * 128 + itile * 2 + it) * 4 + ks * 2 + h) * 32 + il) * 8);

    const size_t kbase = (size_t)(b * 128 + jj * 64) * 1024 + h * 256 + il * 8;
    const size_t vbase = (size_t)(b * 128 + jj * 64) * 8192 + h * 2048 + (cbase + il) * 8;

    f32x16 zf;
    #pragma unroll
    for (int r = 0; r < 16; ++r) zf[r] = 0.f;
    f32x16 acc[2][2];    // [it][ct]
    #pragma unroll
    for (int a = 0; a < 2; ++a)
        #pragma unroll
        for (int c2 = 0; c2 < 2; ++c2) acc[a][c2] = zf;
    float ls[2][2] = {{0.f, 0.f}, {0.f, 0.f}};

    Stage A, B;
    auto load = [&](Stage& S, int jt) {
        const unsigned short* kp = kfrag + kbase + (size_t)jt * 1024;
        S.k0  = *(const short8_t*)kp;
        S.k1  = *(const short8_t*)(kp + 512);
        const unsigned short* vp = vfrag + vbase + (size_t)jt * 8192;
        S.v00 = *(const short8_t*)vp;            // ct0, kp0
        S.v01 = *(const short8_t*)(vp + 4096);   // ct0, kp1
        S.v10 = *(const short8_t*)(vp + 256);    // ct1, kp0
        S.v11 = *(const short8_t*)(vp + 4352);   // ct1, kp1
    };
    auto compute = [&](const Stage& S) {
        f32x16 s0 = MFMA32(S.k0, qf[0][0], zf);
        s0 = MFMA32(S.k1, qf[0][1], s0);
        f32x16 s1 = MFMA32(S.k0, qf[1][0], zf);
        s1 = MFMA32(S.k1, qf[1][1], s1);
        unsigned int bf0[2][4], bf1[2][4];
        make_bfrag(s0, ls[0][0], ls[0][1], bf0);
        make_bfrag(s1, ls[1][0], ls[1][1], bf1);
        acc[0][0] = MFMA32(S.v00, u4_to_s8(bf0[0]), acc[0][0]);
        acc[0][0] = MFMA32(S.v01, u4_to_s8(bf0[1]), acc[0][0]);
        acc[0][1] = MFMA32(S.v10, u4_to_s8(bf0[0]), acc[0][1]);
        acc[0][1] = MFMA32(S.v11, u4_to_s8(bf0[1]), acc[0][1]);
        acc[1][0] = MFMA32(S.v00, u4_to_s8(bf1[0]), acc[1][0]);
        acc[1][0] = MFMA32(S.v01, u4_to_s8(bf1[1]), acc[1][0]);
        acc[1][1] = MFMA32(S.v10, u4_to_s8(bf1[0]), acc[1][1]);
        acc[1][1] = MFMA32(S.v11, u4_to_s8(bf1[1]), acc[1][1]);
    };

    load(A, 0);
    load(B, 1);
    for (int jt = 0; jt < 64; jt += 2) {
        compute(A);
        if (jt + 2 < 64) load(A, jt + 2);
        compute(B);
        if (jt + 3 < 64) load(B, jt + 3);
    }

    // ---- combine j-halves (partner wave w^4) and write out ----
    float l[2];
    #pragma unroll
    for (int it = 0; it < 2; ++it) {
        l[it] = ls[it][0] + ls[it][1];
        l[it] += __shfl_xor(l[it], 32);      // combine h halves of j rows
    }
    const float gam = gamma[0];

    #pragma unroll
    for (int it = 0; it < 2; ++it) {
        __syncthreads();
        #pragma unroll
        for (int r = 0; r < 16; ++r)
            comb[w][lane][r] = jj ? acc[it][0][r] : acc[it][1][r];  // ship ct = jj^1
        comb[w][lane][16] = l[it];
        __syncthreads();
        const int pw = w ^ 4;
        const float lt = l[it] + comb[pw][lane][16];
        const float sc = gam / lt;
        #pragma unroll
        for (int r = 0; r < 16; ++r) {
            const float o = (jj ? acc[it][1][r] : acc[it][0][r]) + comb[pw][lane][r];
            const int c = cbase + jj * 32 + (r & 3) + 8 * (r >> 2) + 4 * h;
            const size_t idx = ((size_t)(b * CCH + c)) * NPIX + i0 + it * 32 + il;
            out[idx] = x[idx] + o * sc;
        }
    }
}

// ---------------------------------------------------------------------------
// Workspace (bf16 elems):
//   wbf[81920] | xfrag[4194304] | qfrag[524288] | kfrag[524288] | vfrag[4194304]
// = 9,519,104 elems = 19.1 MB.
// ---------------------------------------------------------------------------
extern "C" void kernel_launch(void* const* d_in, const int* in_sizes, int n_in,
                              void* d_out, int out_size, void* d_ws, size_t ws_size,
                              hipStream_t stream) {
    const float* x     = (const float*)d_in[0];
    const float* Wq    = (const float*)d_in[1];
    const float* bq    = (const float*)d_in[2];
    const float* Wk    = (const float*)d_in[3];
    const float* bk    = (const float*)d_in[4];
    const float* Wv    = (const float*)d_in[5];
    const float* bv    = (const float*)d_in[6];
    const float* gamma = (const float*)d_in[7];
    float* out = (float*)d_out;

    unsigned short* ws    = (unsigned short*)d_ws;
    unsigned short* wbf   = ws;
    unsigned short* xfrag = ws + 81920;
    unsigned short* qfrag = xfrag + (size_t)4194304;
    unsigned short* kfrag = qfrag + (size_t)524288;
    unsigned short* vfrag = kfrag + (size_t)524288;

    wconv_kernel<<<dim3(320), dim3(256), 0, stream>>>(Wq, Wk, Wv, wbf);
    xt_kernel<<<dim3(256), dim3(256), 0, stream>>>(x, xfrag);
    proj_kernel<<<dim3(256), dim3(320), 0, stream>>>(
        xfrag, wbf, bq, bk, bv, qfrag, kfrag, vfrag);
    attn_kernel<<<dim3(256), dim3(512), 0, stream>>>(
        qfrag, kfrag, vfrag, x, gamma, out);
}